// Round 3
// baseline (344.899 us; speedup 1.0000x reference)
//
#include <hip/hip_runtime.h>

// ---------------------------------------------------------------------------
// MoE top-2 sparse. MI355X (gfx950). B=2,L=1024,D=768,E=16,F=3072,K=2
// GEMM structure: A-panel (96 rows x 768 K, bf16) resident in LDS, staged once
// per K-chunk; B weights stream fp32->regs->cvt_pk->MFMA (no B LDS, no
// steady-state barriers). Wave tile 48 x (16*NF) of mfma_f32_16x16x32_bf16.
// ---------------------------------------------------------------------------

#define D_      768
#define E_      16
#define F_      3072
#define NTOK    2048
#define NROWS   4096            // NTOK * topk
#define SEG     384             // per-expert M segment
#define MAXROWS 6144            // E_ * SEG
#define LDT     776             // 768 + 8 pad (bank-spread, m97 modulo class)

typedef __attribute__((ext_vector_type(4))) unsigned int   u32x4;
typedef __attribute__((ext_vector_type(8))) unsigned short u16x8;
typedef __attribute__((ext_vector_type(8))) short          v8bf;
typedef __attribute__((ext_vector_type(4))) float          f32x4;

static __device__ inline unsigned short f2bf(float f) {
    unsigned u = __builtin_bit_cast(unsigned, f);
    u += 0x7fffu + ((u >> 16) & 1u);      // RNE
    return (unsigned short)(u >> 16);
}
static __device__ inline unsigned cvt_pk_bf16(float lo, float hi) {
    unsigned r;
    asm("v_cvt_pk_bf16_f32 %0, %1, %2" : "=v"(r) : "v"(lo), "v"(hi));
    return r;
}

// ---------------------------------------------------------------------------
// 1. Router: softmax over 16, top-2 (ties -> lowest idx), gates = raw probs
// ---------------------------------------------------------------------------
__global__ void router_kernel(const float* __restrict__ x, const float* __restrict__ wr,
                              int* __restrict__ idx, float* __restrict__ gate) {
    const int tok  = blockIdx.x;
    const int lane = threadIdx.x;          // 64
    const float* xr = x + (size_t)tok * D_;

    float xv[12];
#pragma unroll
    for (int j = 0; j < 12; ++j) xv[j] = xr[lane + 64 * j];

    float lg[E_];
#pragma unroll
    for (int e = 0; e < E_; ++e) {
        const float* w = wr + (size_t)e * D_;
        float acc = 0.f;
#pragma unroll
        for (int j = 0; j < 12; ++j) acc += xv[j] * w[lane + 64 * j];
#pragma unroll
        for (int s = 32; s > 0; s >>= 1) acc += __shfl_xor(acc, s, 64);
        lg[e] = acc;
    }

    float m = lg[0];
#pragma unroll
    for (int e = 1; e < E_; ++e) m = fmaxf(m, lg[e]);
    float p[E_], s = 0.f;
#pragma unroll
    for (int e = 0; e < E_; ++e) { p[e] = expf(lg[e] - m); s += p[e]; }
    const float inv = 1.f / s;

    int e0 = 0; float p0 = p[0];
#pragma unroll
    for (int e = 1; e < E_; ++e) if (p[e] > p0) { p0 = p[e]; e0 = e; }
    int e1 = -1; float p1 = -1.f;
#pragma unroll
    for (int e = 0; e < E_; ++e) if (e != e0 && p[e] > p1) { p1 = p[e]; e1 = e; }

    if (lane == 0) {
        idx[tok * 2 + 0] = e0;  gate[tok * 2 + 0] = p0 * inv;
        idx[tok * 2 + 1] = e1;  gate[tok * 2 + 1] = p1 * inv;
    }
}

// ---------------------------------------------------------------------------
// 2. Build: fixed SEG-sized segments per expert. meta[e] = row count (clamped)
// ---------------------------------------------------------------------------
__global__ void build_kernel(const int* __restrict__ idx, const float* __restrict__ gate,
                             int* __restrict__ rowmap, float* __restrict__ rowgate,
                             int* __restrict__ posOf, int* __restrict__ meta) {
    __shared__ int cur[E_];
    const int t = threadIdx.x;             // 256
    if (t < E_) cur[t] = 0;
    __syncthreads();
    for (int i = t; i < MAXROWS; i += 256) { rowmap[i] = 0; rowgate[i] = 0.f; }
    __syncthreads();
    for (int i = t; i < NROWS; i += 256) {
        const int e = idx[i];
        const int o = atomicAdd(&cur[e], 1);
        if (o < SEG) {
            const int pos = e * SEG + o;
            rowmap[pos]  = i >> 1;
            rowgate[pos] = gate[i];
            posOf[i]     = pos;
        } else {
            posOf[i] = e * SEG;            // ~8-sigma overflow; degrade gracefully
        }
    }
    __syncthreads();
    if (t < E_) meta[t] = cur[t] < SEG ? cur[t] : SEG;
}

// ---------------------------------------------------------------------------
// 3. Gather x rows into bf16 Xg[pos][0..D)
// ---------------------------------------------------------------------------
__global__ void gather_kernel(const float* __restrict__ x, const int* __restrict__ rowmap,
                              unsigned short* __restrict__ Xg) {
    const int g = blockIdx.x * 256 + threadIdx.x;       // 8-elem chunk
    const int pos = g / (D_ / 8), c = g % (D_ / 8);
    const int tok = rowmap[pos];
    const float* src = x + (size_t)tok * D_ + c * 8;
    f32x4 a = *(const f32x4*)src;
    f32x4 b = *(const f32x4*)(src + 4);
    u16x8 o;
    o[0] = f2bf(a[0]); o[1] = f2bf(a[1]); o[2] = f2bf(a[2]); o[3] = f2bf(a[3]);
    o[4] = f2bf(b[0]); o[5] = f2bf(b[1]); o[6] = f2bf(b[2]); o[7] = f2bf(b[3]);
    *(u16x8*)(Xg + (size_t)pos * D_ + c * 8) = o;
}

// ---------------------------------------------------------------------------
// 4/5. Per-expert GEMM, A-panel-stationary.
//   Block = (expert e, n-slice nq, m-band of 96 rows). 512 thr = 8 waves
//   (2m x 4n), wave tile 48 x (NF*16). K consumed in KCH chunks of 768;
//   A-panel re-staged per chunk (2 barriers), acc carried across chunks.
//   B: fp32 [E][N][K] -> per-lane dwordx4 pairs -> v_cvt_pk_bf16_f32 -> MFMA.
//   Grid bid = g + E_*NQ*band, g=(e<<NQSH)|nq -> 4 band-blocks sharing a
//   B-stream land on one XCD (bid%8 const) => weights HBM once, L2 re-serve.
//   EPI=0: +bias, exact gelu -> bf16 H.   EPI=1: (+bias)*rowgate -> fp32 Y.
// ---------------------------------------------------------------------------
template <int EPI, int KCH, int NF, int NQSH>
__global__ __launch_bounds__(512, 2)
void gemm_kernel(const unsigned short* __restrict__ Ag, const float* __restrict__ Bw,
                 const float* __restrict__ bias, void* __restrict__ Cout,
                 const float* __restrict__ rowgate, const int* __restrict__ meta,
                 const int K, const int N) {
    constexpr int BCOLS = 4 * 16 * NF;     // 384 (fc1) / 192 (fc2)
    constexpr int NQ    = 1 << NQSH;

    const int bid  = blockIdx.x;
    const int g    = bid & (E_ * NQ - 1);
    const int band = bid >> (4 + NQSH);
    const int e    = g >> NQSH;
    const int nq   = g & (NQ - 1);
    const int cnt  = meta[e];
    if (band * 96 >= cnt) return;          // whole band is padding -> no work
    const int m0 = e * SEG + band * 96;
    const int n0 = nq * BCOLS;

    __shared__ unsigned short As[96][LDT]; // 145.5 KB, single buffer, 1 block/CU

    const int t    = threadIdx.x;
    const int lane = t & 63;
    const int w    = t >> 6;
    const int wm   = w >> 2;               // 0..1 : 48-row half
    const int wn   = w & 3;                // 0..3 : (NF*16)-col slice
    const int r16  = lane & 15;
    const int h    = lane >> 4;            // 0..3

    f32x4 acc[3][NF];
#pragma unroll
    for (int i = 0; i < 3; ++i)
#pragma unroll
        for (int j = 0; j < NF; ++j) acc[i][j] = (f32x4){0.f, 0.f, 0.f, 0.f};

    // per-lane B base: row = n0 + wn*NF*16 + nf*16 + r16, k-offset h*8
    const float* pB = Bw + ((size_t)e * N + n0 + wn * (NF * 16) + r16) * K + h * 8;

    for (int kc = 0; kc < KCH; ++kc) {
        if (kc) __syncthreads();           // all waves done reading before restage
        {   // stage A panel chunk: 96 rows x 768 k (72 KB payload)
            const unsigned short* src = Ag + (size_t)m0 * K + kc * 768;
#pragma unroll
            for (int i = 0; i < 18; ++i) {
                const int c = t + 512 * i;           // 0..9215
                const int row = c / 96, col = c % 96;
                *(u32x4*)&As[row][col * 8] = *(const u32x4*)(src + (size_t)row * K + col * 8);
            }
        }
        __syncthreads();

        const int kb = kc * 768;
        f32x4 plo[NF], phi[NF];
#pragma unroll
        for (int nf = 0; nf < NF; ++nf) {            // prologue: step-0 loads
            const float* p = pB + (size_t)nf * 16 * K + kb;
            plo[nf] = *(const f32x4*)p;  phi[nf] = *(const f32x4*)(p + 4);
        }
#pragma unroll 2
        for (int kt = 0; kt < 24; ++kt) {
            v8bf bc[NF];
#pragma unroll
            for (int nf = 0; nf < NF; ++nf) {        // fp32 -> packed bf16
                u32x4 q;
                q[0] = cvt_pk_bf16(plo[nf][0], plo[nf][1]);
                q[1] = cvt_pk_bf16(plo[nf][2], plo[nf][3]);
                q[2] = cvt_pk_bf16(phi[nf][0], phi[nf][1]);
                q[3] = cvt_pk_bf16(phi[nf][2], phi[nf][3]);
                bc[nf] = __builtin_bit_cast(v8bf, q);
            }
            if (kt + 1 < 24) {                       // prefetch next step
#pragma unroll
                for (int nf = 0; nf < NF; ++nf) {
                    const float* p = pB + (size_t)nf * 16 * K + kb + (kt + 1) * 32;
                    plo[nf] = *(const f32x4*)p;  phi[nf] = *(const f32x4*)(p + 4);
                }
            }
            v8bf af[3];
#pragma unroll
            for (int mf = 0; mf < 3; ++mf)
                af[mf] = *(const v8bf*)&As[wm * 48 + mf * 16 + r16][kt * 32 + h * 8];
#pragma unroll
            for (int mf = 0; mf < 3; ++mf)
#pragma unroll
                for (int nf = 0; nf < NF; ++nf)
                    acc[mf][nf] = __builtin_amdgcn_mfma_f32_16x16x32_bf16(
                        af[mf], bc[nf], acc[mf][nf], 0, 0, 0);
        }
    }

    // epilogue: C/D layout col = lane&15, row = (lane>>4)*4 + reg
#pragma unroll
    for (int mf = 0; mf < 3; ++mf) {
#pragma unroll
        for (int jj = 0; jj < 4; ++jj) {
            const int rr = m0 + wm * 48 + mf * 16 + h * 4 + jj;
            float gt = 0.f;
            if (EPI == 1) gt = rowgate[rr];
#pragma unroll
            for (int nf = 0; nf < NF; ++nf) {
                const int cc = n0 + wn * (NF * 16) + nf * 16 + r16;
                const float v = acc[mf][nf][jj] + bias[e * N + cc];
                if (EPI == 0) {
                    const float ge = 0.5f * v * (1.f + erff(v * 0.70710678118654752f));
                    ((unsigned short*)Cout)[(size_t)rr * N + cc] = f2bf(ge);
                } else {
                    ((float*)Cout)[(size_t)rr * N + cc] = v * gt;
                }
            }
        }
    }
}

// ---------------------------------------------------------------------------
// 6. Combine: out = x + Y[p0] + Y[p1]   (Y already gate-scaled)
// ---------------------------------------------------------------------------
__global__ void combine_kernel(const float* __restrict__ x, const float* __restrict__ Y,
                               const int* __restrict__ posOf, float* __restrict__ out) {
    const int tok = blockIdx.x;
    const int t   = threadIdx.x;           // 192 * 4 = 768
    const int p0 = posOf[tok * 2 + 0];
    const int p1 = posOf[tok * 2 + 1];
    f32x4 v = *(const f32x4*)(x + (size_t)tok * D_ + t * 4);
    v += *(const f32x4*)(Y + (size_t)p0 * D_ + t * 4);
    v += *(const f32x4*)(Y + (size_t)p1 * D_ + t * 4);
    *(f32x4*)(out + (size_t)tok * D_ + t * 4) = v;
}

// ---------------------------------------------------------------------------
extern "C" void kernel_launch(void* const* d_in, const int* in_sizes, int n_in,
                              void* d_out, int out_size, void* d_ws, size_t ws_size,
                              hipStream_t stream) {
    const float* x  = (const float*)d_in[0];
    const float* wr = (const float*)d_in[1];
    const float* w1 = (const float*)d_in[2];
    const float* b1 = (const float*)d_in[3];
    const float* w2 = (const float*)d_in[4];
    const float* b2 = (const float*)d_in[5];
    float* out = (float*)d_out;

    // workspace layout (~66.2 MB)
    char* wsp = (char*)d_ws;
    int*            idxP    = (int*)(wsp + 0);
    float*          gateP   = (float*)(wsp + 16384);
    int*            posOf   = (int*)(wsp + 32768);
    int*            rowmap  = (int*)(wsp + 49152);
    float*          rowgate = (float*)(wsp + 73728);
    int*            meta    = (int*)(wsp + 98304);
    unsigned short* Xg      = (unsigned short*)(wsp + 131072);                    // 9.44 MB
    unsigned short* H       = (unsigned short*)(wsp + 131072 + 9437184);          // 37.75 MB
    float*          Y       = (float*)(wsp + 131072 + 9437184 + 37748736);        // 18.87 MB

    router_kernel<<<NTOK, 64, 0, stream>>>(x, wr, idxP, gateP);
    build_kernel<<<1, 256, 0, stream>>>(idxP, gateP, rowmap, rowgate, posOf, meta);
    gather_kernel<<<MAXROWS * (D_ / 8) / 256, 256, 0, stream>>>(x, rowmap, Xg);
    // fc1: K=768 (1 chunk), N=3072, NF=6 (384 cols/block), NQ=8 -> grid 512
    gemm_kernel<0, 1, 6, 3><<<E_ * 8 * 4, 512, 0, stream>>>(
        Xg, w1, b1, (void*)H, rowgate, meta, D_, F_);
    // fc2: K=3072 (4 chunks), N=768, NF=3 (192 cols/block), NQ=4 -> grid 256
    gemm_kernel<1, 4, 3, 2><<<E_ * 4 * 4, 512, 0, stream>>>(
        H, w2, b2, (void*)Y, rowgate, meta, F_, D_);
    combine_kernel<<<NTOK, 192, 0, stream>>>(x, Y, posOf, out);
}

// Round 4
// 290.511 us; speedup vs baseline: 1.1872x; 1.1872x over previous
//
#include <hip/hip_runtime.h>

// ---------------------------------------------------------------------------
// MoE top-2 sparse. MI355X (gfx950). B=2,L=1024,D=768,E=16,F=3072,K=2
// GEMM: block = whole expert (BM=384) x BN=192, BK=64, 1024 thr (16 waves,
// 4m x 4n, wave tile 96x48). A (bf16) via global_load_lds with pre-swizzled
// per-lane source (T2 XOR swizzle -> conflict-free frag reads). B (fp32
// weights) reg-staged -> v_cvt_pk_bf16 -> swizzled LDS (T14 early/late split).
// Weights stream HBM exactly once (BM covers the expert); token panels are
// re-served by XCD-pinned L2 (bid%8 == e%8). fc2 k-splits 3072 into 4x768
// with bf16 partial planes, summed in combine.
// ---------------------------------------------------------------------------

#define D_      768
#define E_      16
#define F_      3072
#define NTOK    2048
#define NROWS   4096
#define SEG     384
#define MAXROWS 6144
#define BK      64
#define BNW     192

typedef __attribute__((ext_vector_type(4))) unsigned int   u32x4;
typedef __attribute__((ext_vector_type(8))) unsigned short u16x8;
typedef __attribute__((ext_vector_type(8))) short          v8bf;
typedef __attribute__((ext_vector_type(4))) float          f32x4;

static __device__ inline unsigned short f2bf(float f) {
    unsigned u = __builtin_bit_cast(unsigned, f);
    u += 0x7fffu + ((u >> 16) & 1u);      // RNE
    return (unsigned short)(u >> 16);
}
static __device__ __forceinline__ unsigned cvt_pk_bf16(float lo, float hi) {
    unsigned r;
    asm("v_cvt_pk_bf16_f32 %0, %1, %2" : "=v"(r) : "v"(lo), "v"(hi));
    return r;
}
static __device__ __forceinline__ void gll16(const void* g, void* l) {
    __builtin_amdgcn_global_load_lds(
        (const __attribute__((address_space(1))) unsigned int*)g,
        (__attribute__((address_space(3))) unsigned int*)l, 16, 0, 0);
}

// ---------------------------------------------------------------------------
// 1. Router: softmax over 16, top-2 (ties -> lowest idx), gates = raw probs
// ---------------------------------------------------------------------------
__global__ void router_kernel(const float* __restrict__ x, const float* __restrict__ wr,
                              int* __restrict__ idx, float* __restrict__ gate) {
    const int tok  = blockIdx.x;
    const int lane = threadIdx.x;          // 64
    const float* xr = x + (size_t)tok * D_;

    float xv[12];
#pragma unroll
    for (int j = 0; j < 12; ++j) xv[j] = xr[lane + 64 * j];

    float lg[E_];
#pragma unroll
    for (int e = 0; e < E_; ++e) {
        const float* w = wr + (size_t)e * D_;
        float acc = 0.f;
#pragma unroll
        for (int j = 0; j < 12; ++j) acc += xv[j] * w[lane + 64 * j];
#pragma unroll
        for (int s = 32; s > 0; s >>= 1) acc += __shfl_xor(acc, s, 64);
        lg[e] = acc;
    }

    float m = lg[0];
#pragma unroll
    for (int e = 1; e < E_; ++e) m = fmaxf(m, lg[e]);
    float p[E_], s = 0.f;
#pragma unroll
    for (int e = 0; e < E_; ++e) { p[e] = expf(lg[e] - m); s += p[e]; }
    const float inv = 1.f / s;

    int e0 = 0; float p0 = p[0];
#pragma unroll
    for (int e = 1; e < E_; ++e) if (p[e] > p0) { p0 = p[e]; e0 = e; }
    int e1 = -1; float p1 = -1.f;
#pragma unroll
    for (int e = 0; e < E_; ++e) if (e != e0 && p[e] > p1) { p1 = p[e]; e1 = e; }

    if (lane == 0) {
        idx[tok * 2 + 0] = e0;  gate[tok * 2 + 0] = p0 * inv;
        idx[tok * 2 + 1] = e1;  gate[tok * 2 + 1] = p1 * inv;
    }
}

// ---------------------------------------------------------------------------
// 2. Build: fixed SEG-sized segments per expert
// ---------------------------------------------------------------------------
__global__ void build_kernel(const int* __restrict__ idx, const float* __restrict__ gate,
                             int* __restrict__ rowmap, float* __restrict__ rowgate,
                             int* __restrict__ posOf) {
    __shared__ int cur[E_];
    const int t = threadIdx.x;             // 256
    if (t < E_) cur[t] = 0;
    __syncthreads();
    for (int i = t; i < MAXROWS; i += 256) { rowmap[i] = 0; rowgate[i] = 0.f; }
    __syncthreads();
    for (int i = t; i < NROWS; i += 256) {
        const int e = idx[i];
        const int o = atomicAdd(&cur[e], 1);
        if (o < SEG) {
            const int pos = e * SEG + o;
            rowmap[pos]  = i >> 1;
            rowgate[pos] = gate[i];
            posOf[i]     = pos;
        } else {
            posOf[i] = e * SEG;            // ~8-sigma overflow; degrade gracefully
        }
    }
}

// ---------------------------------------------------------------------------
// 3. Gather x rows into bf16 Xg
// ---------------------------------------------------------------------------
__global__ void gather_kernel(const float* __restrict__ x, const int* __restrict__ rowmap,
                              unsigned short* __restrict__ Xg) {
    const int g = blockIdx.x * 256 + threadIdx.x;
    const int pos = g / (D_ / 8), c = g % (D_ / 8);
    const int tok = rowmap[pos];
    const float* src = x + (size_t)tok * D_ + c * 8;
    f32x4 a = *(const f32x4*)src;
    f32x4 b = *(const f32x4*)(src + 4);
    u16x8 o;
    o[0] = f2bf(a[0]); o[1] = f2bf(a[1]); o[2] = f2bf(a[2]); o[3] = f2bf(a[3]);
    o[4] = f2bf(b[0]); o[5] = f2bf(b[1]); o[6] = f2bf(b[2]); o[7] = f2bf(b[3]);
    *(u16x8*)(Xg + (size_t)pos * D_ + c * 8) = o;
}

// ---------------------------------------------------------------------------
// 4/5. Per-expert GEMM.
//   LDS phys layout (both tiles): phys(row,colbyte) = row*128 + (colbyte ^
//   ((row&7)<<4)); global_load_lds sources are pre-swizzled to match.
//   Grid = E_ * NS; bid = (n<<4)|e  -> bid%8 = e%8 pins experts to XCDs.
//   kOff/addBias are runtime so fc2's 4 k-split launches reuse one kernel.
//   EPI=0: +bias, exact gelu -> bf16 H.  EPI=1: (+bias?)*gate -> bf16 plane.
// ---------------------------------------------------------------------------
template <int EPI, int KLEN>
__global__ __launch_bounds__(1024, 4)
void gemm_kernel(const unsigned short* __restrict__ Ag, const float* __restrict__ Bw,
                 const float* __restrict__ bias, unsigned short* __restrict__ Cout,
                 const float* __restrict__ rowgate, const int K, const int N,
                 const int kOff, const int addBias) {
    constexpr int NT = KLEN / BK;

    const int bid = blockIdx.x;
    const int e   = bid & 15;
    const int n   = bid >> 4;
    const int m0  = e * SEG;
    const int n0  = n * BNW;

    __shared__ alignas(16) unsigned short As[2][SEG * BK];   // 2 x 48 KB
    __shared__ alignas(16) unsigned short Bs[2][BNW * BK];   // 2 x 24 KB

    const int t    = threadIdx.x;
    const int lane = t & 63;
    const int wv   = t >> 6;              // 0..15
    const int wm   = wv >> 2;             // 0..3 : 96-row band
    const int wn   = wv & 3;              // 0..3 : 48-col slice
    const int r16  = lane & 15;
    const int h    = lane >> 4;
    const int xorL = (r16 & 7) << 4;

    f32x4 acc[6][3];
#pragma unroll
    for (int i = 0; i < 6; ++i)
#pragma unroll
        for (int j = 0; j < 3; ++j) acc[i][j] = (f32x4){0.f, 0.f, 0.f, 0.f};

    // A-stage lane constants: lane L, chunk j covers rows wv*24+j*8+(L>>3);
    // its 16B slot holds logical colbyte ((L&7)^((L>>3)&7))<<4 of that row.
    const int aRowL = wv * 24 + (lane >> 3);
    const int aColE = (((lane & 7) ^ ((lane >> 3) & 7)) << 3);
    const unsigned short* Asrc = Ag + (size_t)(m0 + aRowL) * K + kOff + aColE;

    // B-stage constants (t < 768): row = t>>2, two 16B bf16 slots per thread
    const int bRow = t >> 2, bQ = t & 3;
    const float* Bsrc = Bw + ((size_t)e * N + n0 + bRow) * K + kOff + bQ * 16;
    const int bIdx0 = bRow * 64 + ((( bQ * 32     ) ^ ((bRow & 7) << 4)) >> 1);
    const int bIdx1 = bRow * 64 + (((bQ * 32 + 16) ^ ((bRow & 7) << 4)) >> 1);

    f32x4 breg[4];

    auto stageA = [&](int buf, int kt) {
#pragma unroll
        for (int j = 0; j < 3; ++j)
            gll16(Asrc + (size_t)j * 8 * K + kt * BK,
                  &As[buf][(wv * 24 + j * 8) * 64]);
    };
    auto loadB = [&](int kt) {
        if (t < 768) {
            const float* p = Bsrc + kt * BK;
#pragma unroll
            for (int i = 0; i < 4; ++i) breg[i] = *(const f32x4*)(p + 4 * i);
        }
    };
    auto writeB = [&](int buf) {
        if (t < 768) {
            u32x4 q0, q1;
            q0[0] = cvt_pk_bf16(breg[0][0], breg[0][1]);
            q0[1] = cvt_pk_bf16(breg[0][2], breg[0][3]);
            q0[2] = cvt_pk_bf16(breg[1][0], breg[1][1]);
            q0[3] = cvt_pk_bf16(breg[1][2], breg[1][3]);
            q1[0] = cvt_pk_bf16(breg[2][0], breg[2][1]);
            q1[1] = cvt_pk_bf16(breg[2][2], breg[2][3]);
            q1[2] = cvt_pk_bf16(breg[3][0], breg[3][1]);
            q1[3] = cvt_pk_bf16(breg[3][2], breg[3][3]);
            *(u32x4*)&Bs[buf][bIdx0] = q0;
            *(u32x4*)&Bs[buf][bIdx1] = q1;
        }
    };
    auto compute = [&](int buf) {
#pragma unroll
        for (int ks = 0; ks < 2; ++ks) {
            const int co = ((ks * 64 + h * 16) ^ xorL) >> 1;   // swizzled elems
            v8bf bfr[3];
#pragma unroll
            for (int nf = 0; nf < 3; ++nf)
                bfr[nf] = *(const v8bf*)&Bs[buf][(wn * 48 + nf * 16 + r16) * 64 + co];
#pragma unroll
            for (int mf = 0; mf < 6; ++mf) {
                const v8bf af = *(const v8bf*)&As[buf][(wm * 96 + mf * 16 + r16) * 64 + co];
#pragma unroll
                for (int nf = 0; nf < 3; ++nf)
                    acc[mf][nf] = __builtin_amdgcn_mfma_f32_16x16x32_bf16(
                        af, bfr[nf], acc[mf][nf], 0, 0, 0);
            }
        }
    };

    stageA(0, 0); loadB(0); writeB(0);
    __syncthreads();
    int cb = 0;
    for (int kt = 0; kt < NT; ++kt) {
        if (kt + 1 < NT) { loadB(kt + 1); stageA(cb ^ 1, kt + 1); }
        compute(cb);
        if (kt + 1 < NT) writeB(cb ^ 1);
        __syncthreads();
        cb ^= 1;
    }

    // epilogue: C/D layout col = lane&15, row = (lane>>4)*4 + reg
#pragma unroll
    for (int mf = 0; mf < 6; ++mf) {
#pragma unroll
        for (int jj = 0; jj < 4; ++jj) {
            const int rr = m0 + wm * 96 + mf * 16 + h * 4 + jj;
            float gt = 0.f;
            if (EPI == 1) gt = rowgate[rr];
#pragma unroll
            for (int nf = 0; nf < 3; ++nf) {
                const int cc = n0 + wn * 48 + nf * 16 + r16;
                float v = acc[mf][nf][jj];
                if (EPI == 0) {
                    v += bias[e * N + cc];
                    const float ge = 0.5f * v * (1.f + erff(v * 0.70710678118654752f));
                    Cout[(size_t)rr * N + cc] = f2bf(ge);
                } else {
                    if (addBias) v += bias[e * N + cc];
                    Cout[(size_t)rr * N + cc] = f2bf(v * gt);
                }
            }
        }
    }
}

// ---------------------------------------------------------------------------
// 6. Combine: out = x + sum_s (Yp_s[p0] + Yp_s[p1]); plane s address passed
//    via base-pointer table packed as two pointers (plane0, planes123).
// ---------------------------------------------------------------------------
__global__ void combine_kernel(const float* __restrict__ x,
                               const unsigned short* __restrict__ Yp0,
                               const unsigned short* __restrict__ Yp123,
                               const int* __restrict__ posOf, float* __restrict__ out,
                               const int nsplit) {
    const int tok = blockIdx.x;
    const int t   = threadIdx.x;           // 192 * 4 = 768
    const int p0 = posOf[tok * 2 + 0];
    const int p1 = posOf[tok * 2 + 1];
    f32x4 v = *(const f32x4*)(x + (size_t)tok * D_ + t * 4);
    for (int s = 0; s < nsplit; ++s) {
        const unsigned short* base = (s == 0) ? Yp0
                                   : Yp123 + (size_t)(s - 1) * MAXROWS * D_;
        const unsigned short* a = base + (size_t)p0 * D_ + t * 4;
        const unsigned short* b = base + (size_t)p1 * D_ + t * 4;
#pragma unroll
        for (int i = 0; i < 4; ++i) {
            v[i] += __builtin_bit_cast(float, (unsigned)a[i] << 16);
            v[i] += __builtin_bit_cast(float, (unsigned)b[i] << 16);
        }
    }
    *(f32x4*)(out + (size_t)tok * D_ + t * 4) = v;
}

// ---------------------------------------------------------------------------
extern "C" void kernel_launch(void* const* d_in, const int* in_sizes, int n_in,
                              void* d_out, int out_size, void* d_ws, size_t ws_size,
                              hipStream_t stream) {
    const float* x  = (const float*)d_in[0];
    const float* wr = (const float*)d_in[1];
    const float* w1 = (const float*)d_in[2];
    const float* b1 = (const float*)d_in[3];
    const float* w2 = (const float*)d_in[4];
    const float* b2 = (const float*)d_in[5];
    float* out = (float*)d_out;

    char* wsp = (char*)d_ws;
    int*            idxP    = (int*)(wsp + 0);
    float*          gateP   = (float*)(wsp + 16384);
    int*            posOf   = (int*)(wsp + 32768);
    int*            rowmap  = (int*)(wsp + 49152);
    float*          rowgate = (float*)(wsp + 73728);
    const size_t    XG_OFF  = 131072;
    const size_t    PLANE   = (size_t)MAXROWS * D_ * 2;        // 9.44 MB
    const size_t    H_OFF   = XG_OFF + PLANE;
    const size_t    H_BYTES = (size_t)MAXROWS * F_ * 2;        // 37.75 MB
    unsigned short* Xg    = (unsigned short*)(wsp + XG_OFF);
    unsigned short* H     = (unsigned short*)(wsp + H_OFF);
    unsigned short* Yp0   = Xg;                                // plane 0 overlays Xg
    unsigned short* Yp123 = (unsigned short*)(wsp + H_OFF + H_BYTES);

    const bool split4 = (ws_size >= H_OFF + H_BYTES + 3 * PLANE);  // ~75.6 MB

    router_kernel<<<NTOK, 64, 0, stream>>>(x, wr, idxP, gateP);
    build_kernel<<<1, 256, 0, stream>>>(idxP, gateP, rowmap, rowgate, posOf);
    gather_kernel<<<MAXROWS * (D_ / 8) / 256, 256, 0, stream>>>(x, rowmap, Xg);

    // fc1: K=768, N=3072, 16 n-slices. grid 256 x 1024thr (1 block/CU)
    gemm_kernel<0, 768><<<E_ * 16, 1024, 0, stream>>>(
        Xg, w1, b1, H, rowgate, D_, F_, 0, 1);

    if (split4) {
        // fc2: 4 k-split launches of 768 each (4 n-slices -> grid 64 per split;
        // launched back-to-back they co-occupy the chip like one 256-block grid)
        gemm_kernel<1, 768><<<E_ * 4, 1024, 0, stream>>>(
            H, w2, b2, Yp0, rowgate, F_, D_, 0, 1);
        for (int s = 1; s < 4; ++s)
            gemm_kernel<1, 768><<<E_ * 4, 1024, 0, stream>>>(
                H, w2, b2, Yp123 + (size_t)(s - 1) * MAXROWS * D_,
                rowgate, F_, D_, s * 768, 0);
        combine_kernel<<<NTOK, 192, 0, stream>>>(x, Yp0, Yp123, posOf, out, 4);
    } else {
        gemm_kernel<1, 3072><<<E_ * 4, 1024, 0, stream>>>(
            H, w2, b2, Yp0, rowgate, F_, D_, 0, 1);
        combine_kernel<<<NTOK, 192, 0, stream>>>(x, Yp0, Yp123, posOf, out, 1);
    }
}

// Round 5
// 154.127 us; speedup vs baseline: 2.2378x; 1.8849x over previous
//
#include <hip/hip_runtime.h>

// ---------------------------------------------------------------------------
// MoE top-2 sparse. MI355X (gfx950). B=2,L=1024,D=768,E=16,F=3072,K=2
// GEMM: block = whole expert (BM=384) x BN=192, BK=64, 1024 thr (16 waves,
// 4m x 4n, wave tile 96x48). A (bf16) via global_load_lds with pre-swizzled
// per-lane source (XOR swizzle -> conflict-free frag reads, 0 conflicts R4).
// B (fp32 weights) coalesced slot-linear loads (full-line utilization) ->
// v_cvt_pk_bf16 -> swizzled ds_write_b64. Weights stream HBM/L3 exactly once.
// fc2: K=3072 split 4x768 into bf16 partial planes, ONE 256-block launch.
// ---------------------------------------------------------------------------

#define D_      768
#define E_      16
#define F_      3072
#define NTOK    2048
#define NROWS   4096
#define SEG     384
#define MAXROWS 6144
#define BK      64
#define BNW     192

typedef __attribute__((ext_vector_type(2))) unsigned int   u32x2;
typedef __attribute__((ext_vector_type(4))) unsigned int   u32x4;
typedef __attribute__((ext_vector_type(8))) unsigned short u16x8;
typedef __attribute__((ext_vector_type(8))) short          v8bf;
typedef __attribute__((ext_vector_type(4))) float          f32x4;

static __device__ inline unsigned short f2bf(float f) {
    unsigned u = __builtin_bit_cast(unsigned, f);
    u += 0x7fffu + ((u >> 16) & 1u);      // RNE
    return (unsigned short)(u >> 16);
}
static __device__ __forceinline__ unsigned cvt_pk_bf16(float lo, float hi) {
    unsigned r;
    asm("v_cvt_pk_bf16_f32 %0, %1, %2" : "=v"(r) : "v"(lo), "v"(hi));
    return r;
}
static __device__ __forceinline__ void gll16(const void* g, void* l) {
    __builtin_amdgcn_global_load_lds(
        (const __attribute__((address_space(1))) unsigned int*)g,
        (__attribute__((address_space(3))) unsigned int*)l, 16, 0, 0);
}

// ---------------------------------------------------------------------------
// 1. Router: softmax over 16, top-2 (ties -> lowest idx), gates = raw probs
// ---------------------------------------------------------------------------
__global__ void router_kernel(const float* __restrict__ x, const float* __restrict__ wr,
                              int* __restrict__ idx, float* __restrict__ gate) {
    const int tok  = blockIdx.x;
    const int lane = threadIdx.x;          // 64
    const float* xr = x + (size_t)tok * D_;

    float xv[12];
#pragma unroll
    for (int j = 0; j < 12; ++j) xv[j] = xr[lane + 64 * j];

    float lg[E_];
#pragma unroll
    for (int e = 0; e < E_; ++e) {
        const float* w = wr + (size_t)e * D_;
        float acc = 0.f;
#pragma unroll
        for (int j = 0; j < 12; ++j) acc += xv[j] * w[lane + 64 * j];
#pragma unroll
        for (int s = 32; s > 0; s >>= 1) acc += __shfl_xor(acc, s, 64);
        lg[e] = acc;
    }

    float m = lg[0];
#pragma unroll
    for (int e = 1; e < E_; ++e) m = fmaxf(m, lg[e]);
    float p[E_], s = 0.f;
#pragma unroll
    for (int e = 0; e < E_; ++e) { p[e] = expf(lg[e] - m); s += p[e]; }
    const float inv = 1.f / s;

    int e0 = 0; float p0 = p[0];
#pragma unroll
    for (int e = 1; e < E_; ++e) if (p[e] > p0) { p0 = p[e]; e0 = e; }
    int e1 = -1; float p1 = -1.f;
#pragma unroll
    for (int e = 0; e < E_; ++e) if (e != e0 && p[e] > p1) { p1 = p[e]; e1 = e; }

    if (lane == 0) {
        idx[tok * 2 + 0] = e0;  gate[tok * 2 + 0] = p0 * inv;
        idx[tok * 2 + 1] = e1;  gate[tok * 2 + 1] = p1 * inv;
    }
}

// ---------------------------------------------------------------------------
// 2. Build: fixed SEG-sized segments per expert
// ---------------------------------------------------------------------------
__global__ void build_kernel(const int* __restrict__ idx, const float* __restrict__ gate,
                             int* __restrict__ rowmap, float* __restrict__ rowgate,
                             int* __restrict__ posOf) {
    __shared__ int cur[E_];
    const int t = threadIdx.x;             // 256
    if (t < E_) cur[t] = 0;
    __syncthreads();
    for (int i = t; i < MAXROWS; i += 256) { rowmap[i] = 0; rowgate[i] = 0.f; }
    __syncthreads();
    for (int i = t; i < NROWS; i += 256) {
        const int e = idx[i];
        const int o = atomicAdd(&cur[e], 1);
        if (o < SEG) {
            const int pos = e * SEG + o;
            rowmap[pos]  = i >> 1;
            rowgate[pos] = gate[i];
            posOf[i]     = pos;
        } else {
            posOf[i] = e * SEG;            // ~8-sigma overflow; degrade gracefully
        }
    }
}

// ---------------------------------------------------------------------------
// 3. Gather x rows into bf16 Xg
// ---------------------------------------------------------------------------
__global__ void gather_kernel(const float* __restrict__ x, const int* __restrict__ rowmap,
                              unsigned short* __restrict__ Xg) {
    const int g = blockIdx.x * 256 + threadIdx.x;
    const int pos = g / (D_ / 8), c = g % (D_ / 8);
    const int tok = rowmap[pos];
    const float* src = x + (size_t)tok * D_ + c * 8;
    f32x4 a = *(const f32x4*)src;
    f32x4 b = *(const f32x4*)(src + 4);
    u16x8 o;
    o[0] = f2bf(a[0]); o[1] = f2bf(a[1]); o[2] = f2bf(a[2]); o[3] = f2bf(a[3]);
    o[4] = f2bf(b[0]); o[5] = f2bf(b[1]); o[6] = f2bf(b[2]); o[7] = f2bf(b[3]);
    *(u16x8*)(Xg + (size_t)pos * D_ + c * 8) = o;
}

// ---------------------------------------------------------------------------
// 4/5. Per-expert GEMM.
//   LDS phys layout (both tiles): 16B slot p of row r holds logical slot
//   p ^ (r&7)  (128B rows, 8 slots). A staged by global_load_lds with
//   pre-swizzled global source; B by coalesced f32x4 loads (thread t owns
//   slots {t, t+1024, t+2048} of the 3072-slot step chunk -> every load
//   instruction covers contiguous 256B row segments) + swizzled ds_write_b64.
//   Grid bid = ((split*NN + n) << 4) | e  -> bid%8 = e%8 pins experts to XCDs.
//   EPI=0: +bias, exact gelu -> bf16 H.  EPI=1: (+bias if split0)*gate ->
//   bf16 plane (plane0 = C0, planes 1.. = C123 + (split-1)*MAXROWS*N).
// ---------------------------------------------------------------------------
template <int EPI, int NNSH, int KLEN>
__global__ __launch_bounds__(1024, 4)
void gemm_kernel(const unsigned short* __restrict__ Ag, const float* __restrict__ Bw,
                 const float* __restrict__ bias, unsigned short* __restrict__ C0,
                 unsigned short* __restrict__ C123, const float* __restrict__ rowgate,
                 const int K, const int N) {
    constexpr int NT = KLEN / BK;

    const int bid   = blockIdx.x;
    const int e     = bid & 15;
    const int rest  = bid >> 4;
    const int n     = rest & ((1 << NNSH) - 1);
    const int split = rest >> NNSH;
    const int m0    = e * SEG;
    const int n0    = n * BNW;
    const int kOff  = split * KLEN;

    __shared__ alignas(16) unsigned short As[2][SEG * BK];   // 2 x 48 KB
    __shared__ alignas(16) unsigned short Bs[2][BNW * BK];   // 2 x 24 KB

    const int t    = threadIdx.x;
    const int lane = t & 63;
    const int wv   = t >> 6;              // 0..15
    const int wm   = wv >> 2;             // 0..3 : 96-row band
    const int wn   = wv & 3;              // 0..3 : 48-col slice
    const int r16  = lane & 15;
    const int h    = lane >> 4;
    const int xorL = (r16 & 7) << 4;

    f32x4 acc[6][3];
#pragma unroll
    for (int i = 0; i < 6; ++i)
#pragma unroll
        for (int j = 0; j < 3; ++j) acc[i][j] = (f32x4){0.f, 0.f, 0.f, 0.f};

    // A-stage lane constants (verified R4: 0 bank conflicts, correct):
    // lane L, chunk j covers row wv*24+j*8+(L>>3); its 16B LDS slot (L&7)
    // holds logical slot (L&7)^((L>>3)&7) of that row.
    const int aRowL = wv * 24 + (lane >> 3);
    const int aColE = (((lane & 7) ^ ((lane >> 3) & 7)) << 3);
    const unsigned short* Asrc = Ag + (size_t)(m0 + aRowL) * K + kOff + aColE;

    // B-stage constants: slot s = t + 1024*i of 3072 slots (16B fp32 each);
    // row r = s>>4 (256B fp32 per row per step), chunk c = s&15.
    int   bRow[3], bOff[3];
    const float* pB[3];
#pragma unroll
    for (int i = 0; i < 3; ++i) {
        const int s = t + 1024 * i;
        const int r = s >> 4, c = s & 15;
        bRow[i] = r;
        pB[i]   = Bw + ((size_t)e * N + n0 + r) * K + kOff + c * 4;
        // bf16 dest (ushort units): 8 bf16 at logical byte c*8 of row r
        bOff[i] = r * 64 + (((c >> 1) ^ (r & 7)) << 3) + (c & 1) * 4;
    }

    f32x4 breg[3];

    auto stageA = [&](int buf, int kt) {
#pragma unroll
        for (int j = 0; j < 3; ++j)
            gll16(Asrc + (size_t)j * 8 * K + kt * BK,
                  &As[buf][(wv * 24 + j * 8) * 64]);
    };
    auto loadB = [&](int kt) {
#pragma unroll
        for (int i = 0; i < 3; ++i) breg[i] = *(const f32x4*)(pB[i] + kt * BK);
    };
    auto writeB = [&](int buf) {
#pragma unroll
        for (int i = 0; i < 3; ++i) {
            u32x2 q;
            q[0] = cvt_pk_bf16(breg[i][0], breg[i][1]);
            q[1] = cvt_pk_bf16(breg[i][2], breg[i][3]);
            *(u32x2*)&Bs[buf][bOff[i]] = q;
        }
    };
    auto compute = [&](int buf) {
#pragma unroll
        for (int ks = 0; ks < 2; ++ks) {
            const int co = ((ks * 64 + h * 16) ^ xorL) >> 1;   // swizzled elems
            v8bf bfr[3];
#pragma unroll
            for (int nf = 0; nf < 3; ++nf)
                bfr[nf] = *(const v8bf*)&Bs[buf][(wn * 48 + nf * 16 + r16) * 64 + co];
#pragma unroll
            for (int mf = 0; mf < 6; ++mf) {
                const v8bf af = *(const v8bf*)&As[buf][(wm * 96 + mf * 16 + r16) * 64 + co];
#pragma unroll
                for (int nf = 0; nf < 3; ++nf)
                    acc[mf][nf] = __builtin_amdgcn_mfma_f32_16x16x32_bf16(
                        af, bfr[nf], acc[mf][nf], 0, 0, 0);
            }
        }
    };

    stageA(0, 0); loadB(0); writeB(0);
    __syncthreads();
    int cb = 0;
    for (int kt = 0; kt < NT; ++kt) {
        if (kt + 1 < NT) { loadB(kt + 1); stageA(cb ^ 1, kt + 1); }
        compute(cb);
        if (kt + 1 < NT) writeB(cb ^ 1);
        __syncthreads();
        cb ^= 1;
    }

    // epilogue: C/D layout col = lane&15, row = (lane>>4)*4 + reg
    unsigned short* myC = (EPI == 0 || split == 0)
                        ? C0 : C123 + (size_t)(split - 1) * MAXROWS * N;
#pragma unroll
    for (int mf = 0; mf < 6; ++mf) {
#pragma unroll
        for (int jj = 0; jj < 4; ++jj) {
            const int rr = m0 + wm * 96 + mf * 16 + h * 4 + jj;
            float gt = 0.f;
            if (EPI == 1) gt = rowgate[rr];
#pragma unroll
            for (int nf = 0; nf < 3; ++nf) {
                const int cc = n0 + wn * 48 + nf * 16 + r16;
                float v = acc[mf][nf][jj];
                if (EPI == 0) {
                    v += bias[e * N + cc];
                    const float ge = 0.5f * v * (1.f + erff(v * 0.70710678118654752f));
                    myC[(size_t)rr * N + cc] = f2bf(ge);
                } else {
                    if (split == 0) v += bias[e * N + cc];
                    myC[(size_t)rr * N + cc] = f2bf(v * gt);
                }
            }
        }
    }
}

// ---------------------------------------------------------------------------
// 6. Combine: out = x + sum_s (Yp_s[p0] + Yp_s[p1])
// ---------------------------------------------------------------------------
__global__ void combine_kernel(const float* __restrict__ x,
                               const unsigned short* __restrict__ Yp0,
                               const unsigned short* __restrict__ Yp123,
                               const int* __restrict__ posOf, float* __restrict__ out,
                               const int nsplit) {
    const int tok = blockIdx.x;
    const int t   = threadIdx.x;           // 192 * 4 = 768
    const int p0 = posOf[tok * 2 + 0];
    const int p1 = posOf[tok * 2 + 1];
    f32x4 v = *(const f32x4*)(x + (size_t)tok * D_ + t * 4);
    for (int s = 0; s < nsplit; ++s) {
        const unsigned short* base = (s == 0) ? Yp0
                                   : Yp123 + (size_t)(s - 1) * MAXROWS * D_;
        const unsigned short* a = base + (size_t)p0 * D_ + t * 4;
        const unsigned short* b = base + (size_t)p1 * D_ + t * 4;
#pragma unroll
        for (int i = 0; i < 4; ++i) {
            v[i] += __builtin_bit_cast(float, (unsigned)a[i] << 16);
            v[i] += __builtin_bit_cast(float, (unsigned)b[i] << 16);
        }
    }
    *(f32x4*)(out + (size_t)tok * D_ + t * 4) = v;
}

// ---------------------------------------------------------------------------
extern "C" void kernel_launch(void* const* d_in, const int* in_sizes, int n_in,
                              void* d_out, int out_size, void* d_ws, size_t ws_size,
                              hipStream_t stream) {
    const float* x  = (const float*)d_in[0];
    const float* wr = (const float*)d_in[1];
    const float* w1 = (const float*)d_in[2];
    const float* b1 = (const float*)d_in[3];
    const float* w2 = (const float*)d_in[4];
    const float* b2 = (const float*)d_in[5];
    float* out = (float*)d_out;

    char* wsp = (char*)d_ws;
    int*            idxP    = (int*)(wsp + 0);
    float*          gateP   = (float*)(wsp + 16384);
    int*            posOf   = (int*)(wsp + 32768);
    int*            rowmap  = (int*)(wsp + 49152);
    float*          rowgate = (float*)(wsp + 73728);
    const size_t    XG_OFF  = 131072;
    const size_t    PLANE   = (size_t)MAXROWS * D_ * 2;        // 9.44 MB
    const size_t    H_OFF   = XG_OFF + PLANE;
    const size_t    H_BYTES = (size_t)MAXROWS * F_ * 2;        // 37.75 MB
    unsigned short* Xg    = (unsigned short*)(wsp + XG_OFF);
    unsigned short* H     = (unsigned short*)(wsp + H_OFF);
    unsigned short* Yp0   = Xg;                                // plane 0 overlays Xg
    unsigned short* Yp123 = (unsigned short*)(wsp + H_OFF + H_BYTES);

    const bool split4 = (ws_size >= H_OFF + H_BYTES + 3 * PLANE);  // ~75.6 MB

    router_kernel<<<NTOK, 64, 0, stream>>>(x, wr, idxP, gateP);
    build_kernel<<<1, 256, 0, stream>>>(idxP, gateP, rowmap, rowgate, posOf);
    gather_kernel<<<MAXROWS * (D_ / 8) / 256, 256, 0, stream>>>(x, rowmap, Xg);

    // fc1: K=768, N=3072, 16 n-slices, split=0. grid 256 x 1024thr
    gemm_kernel<0, 4, 768><<<E_ * 16, 1024, 0, stream>>>(
        Xg, w1, b1, H, (unsigned short*)nullptr, rowgate, D_, F_);

    if (split4) {
        // fc2: K=3072 as 4x768 k-splits, 4 n-slices -> ONE grid of 256 blocks
        gemm_kernel<1, 2, 768><<<E_ * 16, 1024, 0, stream>>>(
            H, w2, b2, Yp0, Yp123, rowgate, F_, D_);
        combine_kernel<<<NTOK, 192, 0, stream>>>(x, Yp0, Yp123, posOf, out, 4);
    } else {
        // fallback: full K in one pass, grid 64 (split decodes to 0)
        gemm_kernel<1, 2, 3072><<<E_ * 4, 1024, 0, stream>>>(
            H, w2, b2, Yp0, Yp123, rowgate, F_, D_);
        combine_kernel<<<NTOK, 192, 0, stream>>>(x, Yp0, Yp123, posOf, out, 1);
    }
}